// Round 2
// baseline (187.655 us; speedup 1.0000x reference)
//
#include <hip/hip_runtime.h>

typedef __attribute__((ext_vector_type(8))) short frag8;     // 8 bf16 = 4 VGPRs
typedef __attribute__((ext_vector_type(4))) float f4;
typedef __attribute__((ext_vector_type(4))) unsigned int u4;
typedef __attribute__((ext_vector_type(2))) float f2;

namespace {
constexpr int T_STEPS = 25;
constexpr int IN_F    = 14;
constexpr int H       = 24;
// Two independent batch-groups per wave (32 elems per block) for in-wave ILP.
// Rolling x-staging per group: 2 buffers x 4 steps x 1024 B.
constexpr int CHUNK_B   = 4 * 1024;            // one 4-step chunk
constexpr int GROUP_BUF = 2 * CHUNK_B;         // 8 KiB per (wave, group)
constexpr int WAVE_BUF  = 2 * GROUP_BUF;       // 16 KiB per wave
// Pad-free M=96 layout (6 tiles of 16 rows):
//   tile t<4, row m      -> gate t,   unit m        (m = 0..15)
//   tile 4,  row m       -> gate m&3, unit 16+(m>>2)
//   tile 5,  row m       -> gate m&3, unit 20+(m>>2)
// C/D lane (q=lane>>4, col=lane&15) holds rows m=4q+r -> all 4 gates of units
// {4q+r (r=0..3), 16+q, 20+q} = 6 real units, no padding.
// Wh B-operand k-slot map (k = 8q'+j): j<4 -> unit 4q'+j; j=4 -> 16+q';
// j=5 -> 20+q'; j>=6 -> zero. A lane's OUTPUT units == its own B k-slots
// -> recurrent h stays in registers.
// d_ws: shorts [0..12288): frags ((dir*2+set)*6+tile)*64+lane, 8 shorts.
//   Pre-scaled per gate: i,f,o rows * (-log2e), g rows * (2*log2e).
//   set 0 = Wx: k 0..13 = Wx[f] (x_hi), 14..27 = Wx[f-14] (x_lo),
//           k 28 = bias_hi, 29 = bias_lo, 30..31 = 0
//   set 1 = Wh: k-map above
constexpr float LOG2E    = 1.4426950408889634f;
constexpr float TWOLOG2E = 2.8853900817779268f;
}

#if __has_builtin(__builtin_amdgcn_exp2f)
#define EXP2F(v) __builtin_amdgcn_exp2f(v)
#else
#define EXP2F(v) __expf(0.6931471805599453f * (v))
#endif

__device__ __forceinline__ unsigned short bf16_rne(float f) {
    unsigned int u = __float_as_uint(f);
    u += 0x7fff + ((u >> 16) & 1);
    return (unsigned short)(u >> 16);
}
__device__ __forceinline__ float bf16_to_f(unsigned short s) {
    return __uint_as_float(((unsigned int)s) << 16);
}
__device__ __forceinline__ float fast_rcp(float x) { return __builtin_amdgcn_rcpf(x); }

__global__ void pack_mfma(const float* __restrict__ wif, const float* __restrict__ whf,
                          const float* __restrict__ bif, const float* __restrict__ bhf,
                          const float* __restrict__ wib, const float* __restrict__ whb,
                          const float* __restrict__ bib, const float* __restrict__ bhb,
                          unsigned short* __restrict__ ws)
{
    const int gid = blockIdx.x * 256 + threadIdx.x;
    if (gid >= 1536) return;                 // 2 dir * 2 sets * 6 tiles * 64 lanes
    const int lane = gid & 63;
    const int tile = (gid >> 6) % 6;
    const int set  = (gid / 384) & 1;
    const int dir  = gid / 768;
    const int m = lane & 15, q = lane >> 4;  // A-frag: row-in-tile m, k = q*8+j
    // row -> (gate, unit)
    const int g = (tile < 4) ? tile : (m & 3);
    const int u_row = (tile < 4) ? m : ((tile == 4 ? 16 : 20) + (m >> 2));
    const float* Wx = dir ? wib : wif;
    const float* Wh = dir ? whb : whf;
    const float* bi = dir ? bib : bif;
    const float* bh = dir ? bhb : bhf;
    const int rowW = g * 24 + u_row;         // original weight row
    const float scale = (g == 2) ? TWOLOG2E : -LOG2E;   // g-gate vs i,f,o
    unsigned short vals[8];
    #pragma unroll
    for (int j = 0; j < 8; ++j) {
        const int k = q * 8 + j;
        unsigned short o = 0;
        if (set == 0) {
            if (k < 28) {
                const int f = (k < 14) ? k : k - 14;
                o = bf16_rne(scale * Wx[rowW * IN_F + f]);
            } else if (k < 30) {
                const float b = scale * (bi[rowW] + bh[rowW]);
                const unsigned short hi = bf16_rne(b);
                o = (k == 28) ? hi : bf16_rne(b - bf16_to_f(hi));
            }
        } else {
            const int j7 = k & 7, kq = k >> 3;
            int uh = -1;
            if (j7 < 4)       uh = kq * 4 + j7;
            else if (j7 == 4) uh = 16 + kq;
            else if (j7 == 5) uh = 20 + kq;
            if (uh >= 0) o = bf16_rne(scale * Wh[rowW * H + uh]);
        }
        vals[j] = o;
    }
    unsigned short* d = ws + (size_t)gid * 8;
    #pragma unroll
    for (int j = 0; j < 8; ++j) d[j] = vals[j];
}

// One LSTM step's nonlinear update for 6 units/lane from pre-scaled accs.
// i,f,o hold -a*log2e; g holds 2a*log2e.
// c' = (c*(1+ei)(1+eg) + (eg-1)(1+ef)) * rcp((1+ef)(1+ei)(1+eg))
// h  = (ec-1) * rcp((1+eo)(1+ec)),  ec = exp2(2c'*log2e)
__device__ __forceinline__ void lstm_gates(const f4* acc, f4& cv, float& c_s0, float& c_s1,
                                           f4& Hv, float& h_s0, float& h_s1,
                                           frag8& Bhh, frag8& Bhl)
{
    f4 EI, EF, EG, EO, EC;
    #pragma unroll
    for (int r = 0; r < 4; ++r) {
        EI[r] = EXP2F(acc[0][r]);
        EF[r] = EXP2F(acc[1][r]);
        EG[r] = EXP2F(acc[2][r]);
        EO[r] = EXP2F(acc[3][r]);
    }
    const f4 P  = (EI + 1.0f) * (EG + 1.0f);
    const f4 Df = P * (EF + 1.0f);
    f4 Rf;
    #pragma unroll
    for (int r = 0; r < 4; ++r) Rf[r] = fast_rcp(Df[r]);
    cv = (cv * P + (EG - 1.0f) * (EF + 1.0f)) * Rf;
    #pragma unroll
    for (int r = 0; r < 4; ++r) EC[r] = EXP2F(TWOLOG2E * cv[r]);
    const f4 Do = (EO + 1.0f) * (EC + 1.0f);
    f4 Ro;
    #pragma unroll
    for (int r = 0; r < 4; ++r) Ro[r] = fast_rcp(Do[r]);
    Hv = (EC - 1.0f) * Ro;

    float hs[2];
    float cs[2] = {c_s0, c_s1};
    #pragma unroll
    for (int s = 0; s < 2; ++s) {
        const float ei = EXP2F(acc[4 + s][0]);
        const float ef = EXP2F(acc[4 + s][1]);
        const float eg = EXP2F(acc[4 + s][2]);
        const float eo = EXP2F(acc[4 + s][3]);
        const float P2 = (1.0f + ei) * (1.0f + eg);
        const float cn = (cs[s] * P2 + (eg - 1.0f) * (1.0f + ef))
                         * fast_rcp(P2 * (1.0f + ef));
        cs[s] = cn;
        const float ec = EXP2F(TWOLOG2E * cn);
        hs[s] = (ec - 1.0f) * fast_rcp((1.0f + eo) * (1.0f + ec));
    }
    c_s0 = cs[0]; c_s1 = cs[1];
    h_s0 = hs[0]; h_s1 = hs[1];

    // pack h -> own B-frag k-slots {8q+j}: j0..3 = units 4q+j, j4 = 16+q,
    // j5 = 20+q, j6..7 = zero-weight slots (any value)
    f4 Hl;
    #pragma unroll
    for (int r = 0; r < 4; ++r)
        Hl[r] = Hv[r] - __uint_as_float(__float_as_uint(Hv[r]) & 0xFFFF0000u);
    const float hl4 = hs[0] - __uint_as_float(__float_as_uint(hs[0]) & 0xFFFF0000u);
    const float hl5 = hs[1] - __uint_as_float(__float_as_uint(hs[1]) & 0xFFFF0000u);
    const u4 uh4 = {
        __builtin_amdgcn_perm(__float_as_uint(Hv[1]), __float_as_uint(Hv[0]), 0x07060302u),
        __builtin_amdgcn_perm(__float_as_uint(Hv[3]), __float_as_uint(Hv[2]), 0x07060302u),
        __builtin_amdgcn_perm(__float_as_uint(hs[1]), __float_as_uint(hs[0]), 0x07060302u),
        0u};
    const u4 ul4 = {
        __builtin_amdgcn_perm(__float_as_uint(Hl[1]), __float_as_uint(Hl[0]), 0x07060302u),
        __builtin_amdgcn_perm(__float_as_uint(Hl[3]), __float_as_uint(Hl[2]), 0x07060302u),
        __builtin_amdgcn_perm(__float_as_uint(hl5), __float_as_uint(hl4), 0x07060302u),
        0u};
    Bhh = __builtin_bit_cast(frag8, uh4);
    Bhl = __builtin_bit_cast(frag8, ul4);
}

__global__ __launch_bounds__(128, 2)
void bilstm_mfma(const float* __restrict__ x, const unsigned short* __restrict__ wpk,
                 const float* __restrict__ head_w, const float* __restrict__ head_b,
                 float* __restrict__ out, int B)
{
    __align__(16) __shared__ unsigned char arena[2 * WAVE_BUF];   // 32 KiB total

    const int tid  = threadIdx.x;
    const int wave = __builtin_amdgcn_readfirstlane(tid >> 6);   // 0 = fwd, 1 = bwd
    const int lane = tid & 63;
    const int q    = lane >> 4;
    const int col  = lane & 15;
    const int b0   = blockIdx.x * 32;      // 2 groups x 16 elems

    // resident weight A-fragments: 2 sets x 6 tiles = 48 VGPRs (shared by groups)
    frag8 Aw[2][6];
    #pragma unroll
    for (int s = 0; s < 2; ++s)
        #pragma unroll
        for (int t = 0; t < 6; ++t)
            Aw[s][t] = ((const frag8*)wpk)[((wave * 2 + s) * 6 + t) * 64 + lane];

    unsigned char* wbase = arena + wave * WAVE_BUF;
    unsigned char* bufA0 = wbase;                       // group 0: chunks even
    unsigned char* bufB0 = wbase + CHUNK_B;             //          chunks odd
    unsigned char* bufA1 = wbase + GROUP_BUF;           // group 1
    unsigned char* bufB1 = wbase + GROUP_BUF + CHUNK_B;

    // ---- rolling x staging: chunk c = steps 4c..4c+3, one lane-task per group ----
    // lane -> (slot = lane>>4, elem = lane&15). Chunk 3 has only step 12
    // (lanes >= 16 issue harmless in-bounds loads, skip the write).
    unsigned int L0[IN_F], L1[IN_F];

    auto stage_load = [&](int g, int c, unsigned int* xu) {
        const int si = c * 4 + (lane >> 4);            // <= 15 < T_STEPS: safe
        const int e  = lane & 15;
        const int t  = wave ? (T_STEPS - 1 - si) : si;
        const float* xr = x + ((size_t)(b0 + g * 16 + e) * T_STEPS + t) * IN_F;
        #pragma unroll
        for (int i = 0; i < 7; ++i) {
            f2 v = *(const f2*)(xr + 2 * i);
            xu[2*i] = __float_as_uint(v.x); xu[2*i+1] = __float_as_uint(v.y);
        }
    };

    // frag layout per (step, elem): k 0..13 = x_hi (trunc), 14..27 = x_lo,
    // 28..29 = 1.0 (bias rows in A), 30..31 = 0
    auto stage_write = [&](int c, const unsigned int* xu, unsigned char* buf) {
        if (c == 3 && lane >= 16) return;
        const int sl = lane >> 4;
        const int e  = lane & 15;
        unsigned int lo[IN_F];
        #pragma unroll
        for (int i = 0; i < IN_F; ++i)
            lo[i] = __float_as_uint(__uint_as_float(xu[i])
                                    - __uint_as_float(xu[i] & 0xFFFF0000u));
        unsigned int w[16];
        #pragma unroll
        for (int i = 0; i < 7; ++i)
            w[i] = __builtin_amdgcn_perm(xu[2*i+1], xu[2*i], 0x07060302u);   // {hi16,hi16}
        w[7] = __builtin_amdgcn_perm(lo[1], lo[0], 0x07060302u);
        #pragma unroll
        for (int i = 0; i < 6; ++i)
            w[8 + i] = __builtin_amdgcn_perm(lo[2*i+3], lo[2*i+2], 0x07060302u);
        w[14] = 0x3F803F80u;   // bf16 {1.0, 1.0} -> bias rows in A
        w[15] = 0u;
        #pragma unroll
        for (int qq = 0; qq < 4; ++qq)
            *(u4*)(buf + sl * 1024 + qq * 256 + e * 16) =
                (u4){w[qq*4], w[qq*4+1], w[qq*4+2], w[qq*4+3]};
    };

    // per-group recurrent state (explicit names: no runtime-indexed arrays)
    f4    cv0 = {0.f, 0.f, 0.f, 0.f}, cv1 = {0.f, 0.f, 0.f, 0.f};
    float c0a = 0.f, c0b = 0.f, c1a = 0.f, c1b = 0.f;
    f4    Hv0, Hv1;
    float h0a, h0b, h1a, h1b;
    frag8 Bhh0, Bhl0, Bhh1, Bhl1;
    const f4 zc = {0.f, 0.f, 0.f, 0.f};

    const int xoff = q * 256 + col * 16;

    // one full recurrent step for BOTH groups (independent chains interleave)
    auto full_step2 = [&](const unsigned char* bp0, const unsigned char* bp1, int r) {
        const frag8 Bx0 = *(const frag8*)(bp0 + r * 1024 + xoff);
        const frag8 Bx1 = *(const frag8*)(bp1 + r * 1024 + xoff);
        f4 acc0[6], acc1[6];
        #pragma unroll
        for (int t = 0; t < 6; ++t) {
            acc0[t] = __builtin_amdgcn_mfma_f32_16x16x32_bf16(Aw[0][t], Bx0,  zc,      0, 0, 0);
            acc1[t] = __builtin_amdgcn_mfma_f32_16x16x32_bf16(Aw[0][t], Bx1,  zc,      0, 0, 0);
            acc0[t] = __builtin_amdgcn_mfma_f32_16x16x32_bf16(Aw[1][t], Bhh0, acc0[t], 0, 0, 0);
            acc1[t] = __builtin_amdgcn_mfma_f32_16x16x32_bf16(Aw[1][t], Bhh1, acc1[t], 0, 0, 0);
            acc0[t] = __builtin_amdgcn_mfma_f32_16x16x32_bf16(Aw[1][t], Bhl0, acc0[t], 0, 0, 0);
            acc1[t] = __builtin_amdgcn_mfma_f32_16x16x32_bf16(Aw[1][t], Bhl1, acc1[t], 0, 0, 0);
        }
        lstm_gates(acc0, cv0, c0a, c0b, Hv0, h0a, h0b, Bhh0, Bhl0);
        lstm_gates(acc1, cv1, c1a, c1b, Hv1, h1a, h1b, Bhh1, Bhl1);
    };

    // ---- prologue: stage chunk 0 direct, issue chunk-1 loads ----
    stage_load(0, 0, L0);
    stage_load(1, 0, L1);
    stage_write(0, L0, bufA0);
    stage_write(0, L1, bufA1);
    stage_load(0, 1, L0);                  // in flight across steps 0..3
    stage_load(1, 1, L1);

    // ---- step 0 (h = 0: x-product + bias rows only) ----
    {
        const frag8 Bx0 = *(const frag8*)(bufA0 + xoff);
        const frag8 Bx1 = *(const frag8*)(bufA1 + xoff);
        f4 acc0[6], acc1[6];
        #pragma unroll
        for (int t = 0; t < 6; ++t) {
            acc0[t] = __builtin_amdgcn_mfma_f32_16x16x32_bf16(Aw[0][t], Bx0, zc, 0, 0, 0);
            acc1[t] = __builtin_amdgcn_mfma_f32_16x16x32_bf16(Aw[0][t], Bx1, zc, 0, 0, 0);
        }
        lstm_gates(acc0, cv0, c0a, c0b, Hv0, h0a, h0b, Bhh0, Bhl0);
        lstm_gates(acc1, cv1, c1a, c1b, Hv1, h1a, h1b, Bhh1, Bhl1);
    }

    // ---- steps 1..3 from chunk 0 ----
    #pragma unroll 1
    for (int r = 1; r < 4; ++r) full_step2(bufA0, bufA1, r);

    // ---- chunks 1..2: write staged regs, issue next loads, compute 4 steps ----
    #pragma unroll 1
    for (int cc = 1; cc <= 2; ++cc) {
        unsigned char* wb0 = (cc & 1) ? bufB0 : bufA0;
        unsigned char* wb1 = (cc & 1) ? bufB1 : bufA1;
        stage_write(cc, L0, wb0);          // vmcnt-waits loads issued a chunk ago
        stage_write(cc, L1, wb1);
        stage_load(0, cc + 1, L0);         // cc+1==3: lanes>=16 load harmlessly
        stage_load(1, cc + 1, L1);
        #pragma unroll 1
        for (int r = 0; r < 4; ++r) full_step2(wb0, wb1, r);
    }

    // ---- chunk 3: single step 12 ----
    stage_write(3, L0, bufB0);
    stage_write(3, L1, bufB1);
    full_step2(bufB0, bufB1, 0);

    // final h (fp32) -> own wave region (x staging is dead)
    // group g elem col: base wbase + g*1536 + col*96; unit u at +u*4
    {
        unsigned char* h0 = wbase + col * 96;
        *(f4*)(h0 + q * 16) = Hv0;                      // units 4q+r
        *(float*)(h0 + 64 + q * 4) = h0a;               // unit 16+q
        *(float*)(h0 + 80 + q * 4) = h0b;               // unit 20+q
        unsigned char* h1 = wbase + 1536 + col * 96;
        *(f4*)(h1 + q * 16) = Hv1;
        *(float*)(h1 + 64 + q * 4) = h1a;
        *(float*)(h1 + 80 + q * 4) = h1b;
    }

    __syncthreads();   // only cross-wave point: head reads both directions' h

    // head: 128 threads = 32 elems x 4 classes
    {
        const int e = tid >> 2, cls = tid & 3;
        const int hoff = (e >> 4) * 1536 + (e & 15) * 96;
        float acc = head_b[cls];
        const float* hf = (const float*)(arena + hoff);               // fwd
        const float* hb = (const float*)(arena + WAVE_BUF + hoff);    // bwd
        #pragma unroll
        for (int u = 0; u < H; ++u)
            acc += hf[u] * head_w[cls * 2 * H + u] + hb[u] * head_w[cls * 2 * H + H + u];
        out[(size_t)b0 * 4 + tid] = acc;
    }
}

extern "C" void kernel_launch(void* const* d_in, const int* in_sizes, int n_in,
                              void* d_out, int out_size, void* d_ws, size_t ws_size,
                              hipStream_t stream)
{
    const float* x      = (const float*)d_in[0];
    const float* w_ih_f = (const float*)d_in[1];
    const float* w_hh_f = (const float*)d_in[2];
    const float* b_ih_f = (const float*)d_in[3];
    const float* b_hh_f = (const float*)d_in[4];
    const float* w_ih_b = (const float*)d_in[5];
    const float* w_hh_b = (const float*)d_in[6];
    const float* b_ih_b = (const float*)d_in[7];
    const float* b_hh_b = (const float*)d_in[8];
    const float* head_w = (const float*)d_in[9];
    const float* head_b = (const float*)d_in[10];
    float* out = (float*)d_out;
    unsigned short* ws = (unsigned short*)d_ws;

    const int B = in_sizes[0] / (T_STEPS * IN_F);

    hipLaunchKernelGGL(pack_mfma, dim3(6), dim3(256), 0, stream,
                       w_ih_f, w_hh_f, b_ih_f, b_hh_f,
                       w_ih_b, w_hh_b, b_ih_b, b_hh_b, ws);
    hipLaunchKernelGGL(bilstm_mfma, dim3((B + 31) / 32), dim3(128), 0, stream,
                       x, ws, head_w, head_b, out, B);
}

// Round 3
// 178.266 us; speedup vs baseline: 1.0527x; 1.0527x over previous
//
#include <hip/hip_runtime.h>

typedef __attribute__((ext_vector_type(8))) short frag8;     // 8 bf16 = 4 VGPRs
typedef __attribute__((ext_vector_type(4))) float f4;
typedef __attribute__((ext_vector_type(4))) unsigned int u4;
typedef __attribute__((ext_vector_type(2))) float f2;

namespace {
constexpr int T_STEPS = 25;
constexpr int IN_F    = 14;
constexpr int H       = 24;
constexpr int NSTEP   = 13;
// Pad-free M=96 layout (6 tiles of 16 rows):
//   tile t<4, row m      -> gate t,   unit m        (m = 0..15)
//   tile 4,  row m       -> gate m&3, unit 16+(m>>2)
//   tile 5,  row m       -> gate m&3, unit 20+(m>>2)
// C/D lane (q=lane>>4, col=lane&15) holds rows m=4q+r -> all 4 gates of units
// {4q+r (r=0..3), 16+q, 20+q} = 6 real units, no padding.
// Wh B-operand k-slot map (k = 8q'+j): j<4 -> unit 4q'+j; j=4 -> 16+q';
// j=5 -> 20+q'; j>=6 -> zero. A lane's OUTPUT units == its own B k-slots
// -> recurrent h stays in registers.
//
// Wx k-slot map (NEW, LDS-free): chosen so B-frag k-group q needs only the
// 8 contiguous bytes x[row][4q..4q+3] (hi AND lo of the same 4 floats):
//   q<3 : j0..3 -> W[f=4q+j] (x_hi slot),  j4..7 -> W[f=4q+(j-4)] (x_lo slot)
//   q==3: j0/j4 -> W[12], j1/j5 -> W[13], j2 -> bias_hi, j3 -> bias_lo,
//         j6..7 -> 0.   B supplies 1.0 at j2,j3 and 0 at j6,j7.
// -> every lane builds its B-fragment from two 8-byte global loads, no LDS.
//
// d_ws: shorts [0..12288): frags ((dir*2+set)*6+tile)*64+lane, 8 shorts.
//   Pre-scaled per gate: i,f,o rows * (-log2e), g rows * (2*log2e).
constexpr float LOG2E    = 1.4426950408889634f;
constexpr float TWOLOG2E = 2.8853900817779268f;
}

#if __has_builtin(__builtin_amdgcn_exp2f)
#define EXP2F(v) __builtin_amdgcn_exp2f(v)
#else
#define EXP2F(v) __expf(0.6931471805599453f * (v))
#endif

__device__ __forceinline__ unsigned short bf16_rne(float f) {
    unsigned int u = __float_as_uint(f);
    u += 0x7fff + ((u >> 16) & 1);
    return (unsigned short)(u >> 16);
}
__device__ __forceinline__ float bf16_to_f(unsigned short s) {
    return __uint_as_float(((unsigned int)s) << 16);
}
__device__ __forceinline__ float fast_rcp(float x) { return __builtin_amdgcn_rcpf(x); }

__global__ void pack_mfma(const float* __restrict__ wif, const float* __restrict__ whf,
                          const float* __restrict__ bif, const float* __restrict__ bhf,
                          const float* __restrict__ wib, const float* __restrict__ whb,
                          const float* __restrict__ bib, const float* __restrict__ bhb,
                          unsigned short* __restrict__ ws)
{
    const int gid = blockIdx.x * 256 + threadIdx.x;
    if (gid >= 1536) return;                 // 2 dir * 2 sets * 6 tiles * 64 lanes
    const int lane = gid & 63;
    const int tile = (gid >> 6) % 6;
    const int set  = (gid / 384) & 1;
    const int dir  = gid / 768;
    const int m = lane & 15, q = lane >> 4;  // A-frag: row-in-tile m, k = q*8+j
    // row -> (gate, unit)
    const int g = (tile < 4) ? tile : (m & 3);
    const int u_row = (tile < 4) ? m : ((tile == 4 ? 16 : 20) + (m >> 2));
    const float* Wx = dir ? wib : wif;
    const float* Wh = dir ? whb : whf;
    const float* bi = dir ? bib : bif;
    const float* bh = dir ? bhb : bhf;
    const int rowW = g * 24 + u_row;         // original weight row
    const float scale = (g == 2) ? TWOLOG2E : -LOG2E;   // g-gate vs i,f,o
    unsigned short vals[8];
    #pragma unroll
    for (int j = 0; j < 8; ++j) {
        unsigned short o = 0;
        if (set == 0) {
            // NEW Wx k-map (see header comment)
            if (q < 3) {
                const int f = 4 * q + (j & 3);
                o = bf16_rne(scale * Wx[rowW * IN_F + f]);
            } else {
                if (j == 0 || j == 4)      o = bf16_rne(scale * Wx[rowW * IN_F + 12]);
                else if (j == 1 || j == 5) o = bf16_rne(scale * Wx[rowW * IN_F + 13]);
                else if (j == 2 || j == 3) {
                    const float b = scale * (bi[rowW] + bh[rowW]);
                    const unsigned short hi = bf16_rne(b);
                    o = (j == 2) ? hi : bf16_rne(b - bf16_to_f(hi));
                }
                // j == 6,7 -> 0
            }
        } else {
            const int k = q * 8 + j;
            const int j7 = k & 7, kq = k >> 3;
            int uh = -1;
            if (j7 < 4)       uh = kq * 4 + j7;
            else if (j7 == 4) uh = 16 + kq;
            else if (j7 == 5) uh = 20 + kq;
            if (uh >= 0) o = bf16_rne(scale * Wh[rowW * H + uh]);
        }
        vals[j] = o;
    }
    unsigned short* d = ws + (size_t)gid * 8;
    #pragma unroll
    for (int j = 0; j < 8; ++j) d[j] = vals[j];
}

// One LSTM step's nonlinear update for 6 units/lane from pre-scaled accs.
// i,f,o hold -a*log2e; g holds 2a*log2e.
// c' = (c*(1+ei)(1+eg) + (eg-1)(1+ef)) * rcp((1+ef)(1+ei)(1+eg))
// h  = (ec-1) * rcp((1+eo)(1+ec)),  ec = exp2(2c'*log2e)
__device__ __forceinline__ void lstm_gates(const f4* acc, f4& cv, float& c_s0, float& c_s1,
                                           f4& Hv, float& h_s0, float& h_s1,
                                           frag8& Bhh, frag8& Bhl)
{
    f4 EI, EF, EG, EO, EC;
    #pragma unroll
    for (int r = 0; r < 4; ++r) {
        EI[r] = EXP2F(acc[0][r]);
        EF[r] = EXP2F(acc[1][r]);
        EG[r] = EXP2F(acc[2][r]);
        EO[r] = EXP2F(acc[3][r]);
    }
    const f4 P  = (EI + 1.0f) * (EG + 1.0f);
    const f4 Df = P * (EF + 1.0f);
    f4 Rf;
    #pragma unroll
    for (int r = 0; r < 4; ++r) Rf[r] = fast_rcp(Df[r]);
    cv = (cv * P + (EG - 1.0f) * (EF + 1.0f)) * Rf;
    #pragma unroll
    for (int r = 0; r < 4; ++r) EC[r] = EXP2F(TWOLOG2E * cv[r]);
    const f4 Do = (EO + 1.0f) * (EC + 1.0f);
    f4 Ro;
    #pragma unroll
    for (int r = 0; r < 4; ++r) Ro[r] = fast_rcp(Do[r]);
    Hv = (EC - 1.0f) * Ro;

    float hs[2];
    float cs[2] = {c_s0, c_s1};
    #pragma unroll
    for (int s = 0; s < 2; ++s) {
        const float ei = EXP2F(acc[4 + s][0]);
        const float ef = EXP2F(acc[4 + s][1]);
        const float eg = EXP2F(acc[4 + s][2]);
        const float eo = EXP2F(acc[4 + s][3]);
        const float P2 = (1.0f + ei) * (1.0f + eg);
        const float cn = (cs[s] * P2 + (eg - 1.0f) * (1.0f + ef))
                         * fast_rcp(P2 * (1.0f + ef));
        cs[s] = cn;
        const float ec = EXP2F(TWOLOG2E * cn);
        hs[s] = (ec - 1.0f) * fast_rcp((1.0f + eo) * (1.0f + ec));
    }
    c_s0 = cs[0]; c_s1 = cs[1];
    h_s0 = hs[0]; h_s1 = hs[1];

    // pack h -> own B-frag k-slots {8q+j}: j0..3 = units 4q+j, j4 = 16+q,
    // j5 = 20+q, j6..7 = zero-weight slots (any value)
    f4 Hl;
    #pragma unroll
    for (int r = 0; r < 4; ++r)
        Hl[r] = Hv[r] - __uint_as_float(__float_as_uint(Hv[r]) & 0xFFFF0000u);
    const float hl4 = hs[0] - __uint_as_float(__float_as_uint(hs[0]) & 0xFFFF0000u);
    const float hl5 = hs[1] - __uint_as_float(__float_as_uint(hs[1]) & 0xFFFF0000u);
    const u4 uh4 = {
        __builtin_amdgcn_perm(__float_as_uint(Hv[1]), __float_as_uint(Hv[0]), 0x07060302u),
        __builtin_amdgcn_perm(__float_as_uint(Hv[3]), __float_as_uint(Hv[2]), 0x07060302u),
        __builtin_amdgcn_perm(__float_as_uint(hs[1]), __float_as_uint(hs[0]), 0x07060302u),
        0u};
    const u4 ul4 = {
        __builtin_amdgcn_perm(__float_as_uint(Hl[1]), __float_as_uint(Hl[0]), 0x07060302u),
        __builtin_amdgcn_perm(__float_as_uint(Hl[3]), __float_as_uint(Hl[2]), 0x07060302u),
        __builtin_amdgcn_perm(__float_as_uint(hl5), __float_as_uint(hl4), 0x07060302u),
        0u};
    Bhh = __builtin_bit_cast(frag8, uh4);
    Bhl = __builtin_bit_cast(frag8, ul4);
}

__global__ __launch_bounds__(128, 4)
void bilstm_mfma(const float* __restrict__ x, const unsigned short* __restrict__ wpk,
                 const float* __restrict__ head_w, const float* __restrict__ head_b,
                 float* __restrict__ out, int B)
{
    // LDS: only the fwd/bwd h exchange for the head (16 elems x 96 B per wave)
    __align__(16) __shared__ unsigned char arena[2 * 1536];

    const int tid  = threadIdx.x;
    const int wave = __builtin_amdgcn_readfirstlane(tid >> 6);   // 0 = fwd, 1 = bwd
    const int lane = tid & 63;
    const int q    = lane >> 4;
    const int col  = lane & 15;
    const int b0   = blockIdx.x * 16;

    // resident weight A-fragments: 2 sets x 6 tiles = 48 VGPRs
    frag8 Aw[2][6];
    #pragma unroll
    for (int s = 0; s < 2; ++s)
        #pragma unroll
        for (int t = 0; t < 6; ++t)
            Aw[s][t] = ((const frag8*)wpk)[((wave * 2 + s) * 6 + t) * 64 + lane];

    // ---- direct global -> B-fragment x path (no LDS, no transpose) ----
    // lane (q,col) needs x[b0+col][t][4q..4q+3]; q==3 needs f12,f13 + bias.
    // q==3 loads bytes 40..55 ({f10,f11,f12,f13}) so all loads are 8B-aligned
    // in-bounds pairs; f12,f13 arrive in the second pair.
    const bool q3 = (q == 3);
    const unsigned int biasor = q3 ? 0x3F803F80u : 0u;   // bf16 {1.0,1.0} at j2,j3
    const int  boff  = q3 ? 40 : q * 16;
    const int  t0    = wave ? (T_STEPS - 1) : 0;
    const int  dstep = wave ? -(IN_F * 4) : (IN_F * 4);
    const char* px = (const char*)x
                   + ((size_t)(b0 + col) * T_STEPS + t0) * (IN_F * 4) + boff;

    auto build_bx = [&](f2 la, f2 lb) -> frag8 {
        const float a0 = q3 ? lb.x : la.x;
        const float a1 = q3 ? lb.y : la.y;
        const float a2 = q3 ? 0.0f : lb.x;
        const float a3 = q3 ? 0.0f : lb.y;
        const float l0 = a0 - __uint_as_float(__float_as_uint(a0) & 0xFFFF0000u);
        const float l1 = a1 - __uint_as_float(__float_as_uint(a1) & 0xFFFF0000u);
        const float l2 = a2 - __uint_as_float(__float_as_uint(a2) & 0xFFFF0000u);
        const float l3 = a3 - __uint_as_float(__float_as_uint(a3) & 0xFFFF0000u);
        const u4 w = {
            __builtin_amdgcn_perm(__float_as_uint(a1), __float_as_uint(a0), 0x07060302u),
            __builtin_amdgcn_perm(__float_as_uint(a3), __float_as_uint(a2), 0x07060302u) | biasor,
            __builtin_amdgcn_perm(__float_as_uint(l1), __float_as_uint(l0), 0x07060302u),
            __builtin_amdgcn_perm(__float_as_uint(l3), __float_as_uint(l2), 0x07060302u)};
        return __builtin_bit_cast(frag8, w);
    };

    f4    cv = {0.f, 0.f, 0.f, 0.f};   // c of units 4q+r
    float c_s0 = 0.f, c_s1 = 0.f;      // c of units 16+q, 20+q
    f4    Hv;                          // h of units 4q+r (fp32, for head)
    float h_s0, h_s1;                  // h of units 16+q, 20+q
    frag8 Bhh, Bhl;                    // recurrent h as B-fragments — registers only
    const f4 zc = {0.f, 0.f, 0.f, 0.f};

    // prologue: load step-0 x
    f2 la = *(const f2*)px;
    f2 lb = *(const f2*)(px + 8);
    px += dstep;

    // ---- step 0 (h = 0: x-product + bias rows only) ----
    {
        const frag8 Bx = build_bx(la, lb);
        la = *(const f2*)px; lb = *(const f2*)(px + 8); px += dstep;   // prefetch s=1
        f4 acc[6];
        #pragma unroll
        for (int t = 0; t < 6; ++t)
            acc[t] = __builtin_amdgcn_mfma_f32_16x16x32_bf16(Aw[0][t], Bx, zc, 0, 0, 0);
        lstm_gates(acc, cv, c_s0, c_s1, Hv, h_s0, h_s1, Bhh, Bhl);
    }

    // ---- steps 1..12: pure-register recurrence, x prefetched 1 step ahead ----
    #pragma unroll 1
    for (int s = 1; s < NSTEP; ++s) {
        const frag8 Bx = build_bx(la, lb);
        // prefetch s+1 (s==12 reads t=13 fwd / t=11 bwd: in-bounds, unused)
        la = *(const f2*)px; lb = *(const f2*)(px + 8); px += dstep;
        f4 acc[6];
        #pragma unroll
        for (int t = 0; t < 6; ++t) {
            acc[t] = __builtin_amdgcn_mfma_f32_16x16x32_bf16(Aw[0][t], Bx,  zc,     0, 0, 0);
            acc[t] = __builtin_amdgcn_mfma_f32_16x16x32_bf16(Aw[1][t], Bhh, acc[t], 0, 0, 0);
            acc[t] = __builtin_amdgcn_mfma_f32_16x16x32_bf16(Aw[1][t], Bhl, acc[t], 0, 0, 0);
        }
        lstm_gates(acc, cv, c_s0, c_s1, Hv, h_s0, h_s1, Bhh, Bhl);
    }

    // final h (fp32) -> own wave region; unit u of elem col at byte col*96 + u*4
    unsigned char* hbase = arena + wave * 1536;
    *(f4*)(hbase + col * 96 + q * 16) = Hv;                       // units 4q+r
    *(float*)(hbase + col * 96 + 64 + q * 4) = h_s0;              // unit 16+q
    *(float*)(hbase + col * 96 + 80 + q * 4) = h_s1;              // unit 20+q

    __syncthreads();   // only cross-wave point: head reads both directions' h

    if (tid < 64) {
        const int e = tid >> 2, cls = tid & 3;
        float acc = head_b[cls];
        const float* hf = (const float*)(arena + e * 96);              // fwd
        const float* hb = (const float*)(arena + 1536 + e * 96);       // bwd
        #pragma unroll
        for (int u = 0; u < H; ++u)
            acc += hf[u] * head_w[cls * 2 * H + u] + hb[u] * head_w[cls * 2 * H + H + u];
        out[(size_t)b0 * 4 + tid] = acc;
    }
}

extern "C" void kernel_launch(void* const* d_in, const int* in_sizes, int n_in,
                              void* d_out, int out_size, void* d_ws, size_t ws_size,
                              hipStream_t stream)
{
    const float* x      = (const float*)d_in[0];
    const float* w_ih_f = (const float*)d_in[1];
    const float* w_hh_f = (const float*)d_in[2];
    const float* b_ih_f = (const float*)d_in[3];
    const float* b_hh_f = (const float*)d_in[4];
    const float* w_ih_b = (const float*)d_in[5];
    const float* w_hh_b = (const float*)d_in[6];
    const float* b_ih_b = (const float*)d_in[7];
    const float* b_hh_b = (const float*)d_in[8];
    const float* head_w = (const float*)d_in[9];
    const float* head_b = (const float*)d_in[10];
    float* out = (float*)d_out;
    unsigned short* ws = (unsigned short*)d_ws;

    const int B = in_sizes[0] / (T_STEPS * IN_F);

    hipLaunchKernelGGL(pack_mfma, dim3(6), dim3(256), 0, stream,
                       w_ih_f, w_hh_f, b_ih_f, b_hh_f,
                       w_ih_b, w_hh_b, b_ih_b, b_hh_b, ws);
    hipLaunchKernelGGL(bilstm_mfma, dim3((B + 15) / 16), dim3(128), 0, stream,
                       x, ws, head_w, head_b, out, B);
}